// Round 8
// baseline (406.237 us; speedup 1.0000x reference)
//
#include <hip/hip_runtime.h>
#include <math.h>

#define HD 256   // hidden dim (fixed per problem)

typedef short bf16x8 __attribute__((ext_vector_type(8)));
typedef float f32x4  __attribute__((ext_vector_type(4)));

__device__ __forceinline__ unsigned short f2bf(float f) {   // RNE f32->bf16
    unsigned u = __builtin_bit_cast(unsigned, f);
    unsigned r = (u + 0x7fffu + ((u >> 16) & 1u)) >> 16;
    return (unsigned short)r;
}
__device__ __forceinline__ float bf2f(unsigned b) {
    return __builtin_bit_cast(float, (b & 0xffffu) << 16);
}

// ---------------- CSR build ----------------

__global__ void init_deg_kernel(int* __restrict__ deg, int* __restrict__ cursor, int n) {
    int i = blockIdx.x * blockDim.x + threadIdx.x;
    if (i < n) { deg[i] = 1; cursor[i] = 0; }   // 1 = self loop
}

__global__ void count_deg_kernel(const int* __restrict__ col, int E, int* __restrict__ deg) {
    int e = blockIdx.x * blockDim.x + threadIdx.x;
    if (e < E) atomicAdd(&deg[col[e]], 1);
}

__global__ __launch_bounds__(1024) void scan_kernel(const int* __restrict__ deg,
                                                    int* __restrict__ offs,
                                                    float* __restrict__ dinv, int n) {
    __shared__ int ps[1024];
    int tid = threadIdx.x;
    int chunk = (n + 1023) >> 10;
    int beg = tid * chunk;
    int end = min(beg + chunk, n);
    int s = 0;
    for (int i = beg; i < end; ++i) s += deg[i];
    ps[tid] = s;
    __syncthreads();
    for (int off = 1; off < 1024; off <<= 1) {
        int t = (tid >= off) ? ps[tid - off] : 0;
        __syncthreads();
        ps[tid] += t;
        __syncthreads();
    }
    int run = ps[tid] - s;  // exclusive prefix
    for (int i = beg; i < end; ++i) {
        offs[i] = run;
        run += deg[i];
        dinv[i] = rsqrtf((float)deg[i]);
    }
    if (tid == 1023) offs[n] = ps[1023];
}

__global__ void fill_csr_kernel(const int* __restrict__ ei, int E, int N,
                                const int* __restrict__ offs,
                                int* __restrict__ cursor, int* __restrict__ csr) {
    int idx = blockIdx.x * blockDim.x + threadIdx.x;
    int tot = E + N;
    if (idx >= tot) return;
    int r, c;
    if (idx < E) { r = ei[idx]; c = ei[E + idx]; }
    else         { r = c = idx - E; }                 // self loop
    int slot = atomicAdd(&cursor[c], 1);
    csr[offs[c] + slot] = r;
}

// ---------------- W pre-pack: f32 W[256][256] -> MFMA-fragment-linear bf16 hi/lo ----------------
// Frag (nc,kc): 16x16x32 B-operand tile, cols nc*16..+15, k kc*32..+31.
// Slot rule (same as A side, so any intra-frag k permutation cancels):
//   lane l, elem e  <->  W[kc*32 + 8*(l>>4) + e][nc*16 + (l&15)]
// Layout (kc-MAJOR so one kc-chunk = contiguous 16 KB for LDS staging):
//   pk[mat][kc][nc][lane][e], 65536 elems per matrix; chunk(kc) = 8192 shorts.

__global__ __launch_bounds__(256) void packW_kernel(const float* __restrict__ W0,
                                                    const float* __restrict__ W1,
                                                    const float* __restrict__ W2,
                                                    const float* __restrict__ W3,
                                                    unsigned short* __restrict__ pkhi,
                                                    unsigned short* __restrict__ pklo) {
    int gid = blockIdx.x * 256 + threadIdx.x;   // 32768 threads total
    int mat  = gid >> 13;
    int rem  = gid & 8191;
    int nc   = rem >> 9;
    int kc   = (rem >> 6) & 7;
    int lane = rem & 63;
    const float* W = (mat == 0) ? W0 : (mat == 1) ? W1 : (mat == 2) ? W2 : W3;
    int col = nc * 16 + (lane & 15);
    int kb  = kc * 32 + (lane >> 4) * 8;
    alignas(16) unsigned short h[8], l[8];
#pragma unroll
    for (int e = 0; e < 8; ++e) {
        float w = W[(size_t)(kb + e) * HD + col];
        unsigned short hb = f2bf(w);
        h[e] = hb;
        l[e] = f2bf(w - bf2f(hb));
    }
    size_t off = (size_t)mat * 65536 + ((size_t)(kc * 16 + nc) * 64 + lane) * 8;
    *(uint4*)&pkhi[off] = *(const uint4*)h;
    *(uint4*)&pklo[off] = *(const uint4*)l;
}

// ---------------- x conversion: thi/tlo = split(dinv[row] * x[row][:]) ----------------

__global__ __launch_bounds__(256) void convx_kernel(const float* __restrict__ x,
                                                    const float* __restrict__ dinv,
                                                    unsigned short* __restrict__ thi,
                                                    unsigned short* __restrict__ tlo, int N) {
    int gid = blockIdx.x * 256 + threadIdx.x;   // N*32, 8 elems each
    if (gid >= N * 32) return;
    int row = gid >> 5;
    int c8  = (gid & 31) * 8;
    float s = dinv[row];
    const float4* xp = (const float4*)(x + (size_t)row * HD + c8);
    float4 v0 = xp[0], v1 = xp[1];
    float vals[8] = {v0.x, v0.y, v0.z, v0.w, v1.x, v1.y, v1.z, v1.w};
    alignas(16) unsigned short h[8], l[8];
#pragma unroll
    for (int e = 0; e < 8; ++e) {
        float t = vals[e] * s;
        unsigned short hb = f2bf(t);
        h[e] = hb;
        l[e] = f2bf(t - bf2f(hb));
    }
    size_t off = (size_t)row * HD + c8;
    *(uint4*)&thi[off] = *(const uint4*)h;
    *(uint4*)&tlo[off] = *(const uint4*)l;
}

// ---------------- aggregation (hidden layers) ----------------
// read f32 z, gather row-sum, t = dinv*relu(dinv*S + b), write split bf16 hi/lo.

__global__ __launch_bounds__(256) void agg_relu_split_kernel(const float* __restrict__ z,
                                                             const int* __restrict__ csr,
                                                             const int* __restrict__ offs,
                                                             const float* __restrict__ dinv,
                                                             const float* __restrict__ bias,
                                                             unsigned short* __restrict__ thi,
                                                             unsigned short* __restrict__ tlo, int N) {
    int gid  = blockIdx.x * blockDim.x + threadIdx.x;
    int v    = gid >> 6;
    int lane = gid & 63;
    if (v >= N) return;

    int beg = offs[v];
    int end = offs[v + 1];
    const float4* hp = (const float4*)z;

    float4 acc = make_float4(0.f, 0.f, 0.f, 0.f);
    int i = beg;
    for (; i + 4 <= end; i += 4) {
        int u0 = csr[i], u1 = csr[i + 1], u2 = csr[i + 2], u3 = csr[i + 3];
        float4 r0 = hp[(size_t)u0 * 64 + lane];
        float4 r1 = hp[(size_t)u1 * 64 + lane];
        float4 r2 = hp[(size_t)u2 * 64 + lane];
        float4 r3 = hp[(size_t)u3 * 64 + lane];
        acc.x += (r0.x + r1.x) + (r2.x + r3.x);
        acc.y += (r0.y + r1.y) + (r2.y + r3.y);
        acc.z += (r0.z + r1.z) + (r2.z + r3.z);
        acc.w += (r0.w + r1.w) + (r2.w + r3.w);
    }
    for (; i < end; ++i) {
        int u = csr[i];
        float4 r = hp[(size_t)u * 64 + lane];
        acc.x += r.x; acc.y += r.y; acc.z += r.z; acc.w += r.w;
    }

    float dv = dinv[v];
    float4 bv = ((const float4*)bias)[lane];
    float t[4];
    t[0] = dv * fmaxf(fmaf(dv, acc.x, bv.x), 0.f);
    t[1] = dv * fmaxf(fmaf(dv, acc.y, bv.y), 0.f);
    t[2] = dv * fmaxf(fmaf(dv, acc.z, bv.z), 0.f);
    t[3] = dv * fmaxf(fmaf(dv, acc.w, bv.w), 0.f);
    alignas(8) unsigned short h[4], l[4];
#pragma unroll
    for (int e = 0; e < 4; ++e) {
        unsigned short hb = f2bf(t[e]);
        h[e] = hb;
        l[e] = f2bf(t[e] - bf2f(hb));
    }
    size_t off = (size_t)v * HD + lane * 4;
    *(uint2*)&thi[off] = *(const uint2*)h;
    *(uint2*)&tlo[off] = *(const uint2*)l;
}

// ---------------- shared aggregation: g = dinv * sum(t2) ----------------

__global__ __launch_bounds__(256) void agg_pair_kernel(const unsigned short* __restrict__ thi,
                                                       const unsigned short* __restrict__ tlo,
                                                       const int* __restrict__ csr,
                                                       const int* __restrict__ offs,
                                                       const float* __restrict__ dinv,
                                                       unsigned short* __restrict__ ghi,
                                                       unsigned short* __restrict__ glo, int N) {
    int gid  = blockIdx.x * blockDim.x + threadIdx.x;
    int v    = gid >> 6;
    int lane = gid & 63;
    if (v >= N) return;

    int beg = offs[v];
    int end = offs[v + 1];
    const uint2* hp = (const uint2*)thi;   // row = 64 uint2 (4 bf16 each)
    const uint2* lp = (const uint2*)tlo;

    float a0 = 0.f, a1 = 0.f, a2 = 0.f, a3 = 0.f;
    int i = beg;
    for (; i + 2 <= end; i += 2) {
        int u0 = csr[i], u1 = csr[i + 1];
        uint2 h0 = hp[(size_t)u0 * 64 + lane];
        uint2 l0 = lp[(size_t)u0 * 64 + lane];
        uint2 h1 = hp[(size_t)u1 * 64 + lane];
        uint2 l1 = lp[(size_t)u1 * 64 + lane];
        a0 += (bf2f(h0.x) + bf2f(l0.x)) + (bf2f(h1.x) + bf2f(l1.x));
        a1 += (bf2f(h0.x >> 16) + bf2f(l0.x >> 16)) + (bf2f(h1.x >> 16) + bf2f(l1.x >> 16));
        a2 += (bf2f(h0.y) + bf2f(l0.y)) + (bf2f(h1.y) + bf2f(l1.y));
        a3 += (bf2f(h0.y >> 16) + bf2f(l0.y >> 16)) + (bf2f(h1.y >> 16) + bf2f(l1.y >> 16));
    }
    for (; i < end; ++i) {
        int u = csr[i];
        uint2 h0 = hp[(size_t)u * 64 + lane];
        uint2 l0 = lp[(size_t)u * 64 + lane];
        a0 += bf2f(h0.x) + bf2f(l0.x);
        a1 += bf2f(h0.x >> 16) + bf2f(l0.x >> 16);
        a2 += bf2f(h0.y) + bf2f(l0.y);
        a3 += bf2f(h0.y >> 16) + bf2f(l0.y >> 16);
    }

    float dv = dinv[v];
    float t[4] = {dv * a0, dv * a1, dv * a2, dv * a3};
    alignas(8) unsigned short h[4], l[4];
#pragma unroll
    for (int e = 0; e < 4; ++e) {
        unsigned short hb = f2bf(t[e]);
        h[e] = hb;
        l[e] = f2bf(t[e] - bf2f(hb));
    }
    size_t off = (size_t)v * HD + lane * 4;
    *(uint2*)&ghi[off] = *(const uint2*)h;
    *(uint2*)&glo[off] = *(const uint2*)l;
}

// ---------------- MFMA GEMM: C[M,256] = (Ahi+Alo) @ (Whi+Wlo), 3-term split ----------------
// W SHARED VIA LDS: per kc, the 16 KB hi + 16 KB lo fragment chunk is staged once
// per block (reg-staged, double-buffered, 1 barrier/kc); all 4 waves consume it
// with contiguous conflict-free ds_read_b128.  This removes the per-wave L2 W
// streaming (was ~256 KB/wave -> L2-port bound at ~56 B/cy/CU).
// Block = 256 thr = 4 waves x 16 rows = 64 rows, FULL 256 cols -> A read once.
// Hidden: grid (ceil(M/64), 1).  HEADS: grid.y=2 selects W2/out2 vs W3/out3.
// mfma_f32_16x16x32_bf16: D col=lane&15, row=(lane>>4)*4+reg  [m89-verified].

template<bool HEADS>
__global__ __launch_bounds__(256)
void gemm_mfma_kernel(const unsigned short* __restrict__ Ahi,
                      const unsigned short* __restrict__ Alo,
                      const unsigned short* __restrict__ pkhi,
                      const unsigned short* __restrict__ pklo,
                      const float* __restrict__ ba,
                      const float* __restrict__ bb,
                      float* __restrict__ Ca,
                      float* __restrict__ Cb, int M) {
    __shared__ unsigned short lds[2][2][8192];   // [buf][hi/lo][16KB], 64 KB total

    const int tid  = threadIdx.x;
    const int lane = tid & 63;
    const int wave = tid >> 6;

    const int sel = HEADS ? blockIdx.y : 0;
    const unsigned short* ph = pkhi + (size_t)sel * 65536;
    const unsigned short* pl = pklo + (size_t)sel * 65536;
    float*       C    = sel ? Cb : Ca;
    const float* bias = sel ? bb : ba;

    const int row0 = blockIdx.x * 64 + wave * 16;
    const int rowA = min(row0 + (lane & 15), M - 1);  // clamp: garbage only feeds unstored rows
    const int kg   = lane >> 4;

    const unsigned short* aH = Ahi + (size_t)rowA * HD + kg * 8;
    const unsigned short* aL = Alo + (size_t)rowA * HD + kg * 8;

    f32x4 acc[16];
#pragma unroll
    for (int nf = 0; nf < 16; ++nf) acc[nf] = (f32x4)0.f;

    uint4 sH[4], sL[4];   // staging regs: thread t carries 4x16B hi + 4x16B lo per chunk

#define LOADC(kc)                                                            \
    {                                                                        \
        const uint4* gh = (const uint4*)(ph + (kc) * 8192);                  \
        const uint4* gl = (const uint4*)(pl + (kc) * 8192);                  \
        _Pragma("unroll")                                                    \
        for (int r = 0; r < 4; ++r) { sH[r] = gh[r * 256 + tid]; sL[r] = gl[r * 256 + tid]; } \
    }
#define WRITEC(buf)                                                          \
    {                                                                        \
        _Pragma("unroll")                                                    \
        for (int r = 0; r < 4; ++r) {                                        \
            *(uint4*)&lds[buf][0][(r * 256 + tid) * 8] = sH[r];              \
            *(uint4*)&lds[buf][1][(r * 256 + tid) * 8] = sL[r];              \
        }                                                                    \
    }

    LOADC(0); WRITEC(0); LOADC(1);
    __syncthreads();

#pragma unroll
    for (int kc = 0; kc < 8; ++kc) {
        const int cur = kc & 1;
        if (kc < 7) WRITEC(cur ^ 1);      // regs hold chunk kc+1 (safe: readers done last barrier)
        if (kc < 6) LOADC(kc + 2);        // prefetch next-next chunk into regs

        bf16x8 ahv = *(const bf16x8*)(aH + kc * 32);
        bf16x8 alv = *(const bf16x8*)(aL + kc * 32);
#pragma unroll
        for (int nf = 0; nf < 16; ++nf) {
            bf16x8 wh = *(const bf16x8*)&lds[cur][0][(nf * 64 + lane) * 8];
            bf16x8 wl = *(const bf16x8*)&lds[cur][1][(nf * 64 + lane) * 8];
            acc[nf] = __builtin_amdgcn_mfma_f32_16x16x32_bf16(ahv, wh, acc[nf], 0, 0, 0);
            acc[nf] = __builtin_amdgcn_mfma_f32_16x16x32_bf16(ahv, wl, acc[nf], 0, 0, 0);
            acc[nf] = __builtin_amdgcn_mfma_f32_16x16x32_bf16(alv, wh, acc[nf], 0, 0, 0);
        }
        __syncthreads();
    }
#undef LOADC
#undef WRITEC

#pragma unroll
    for (int nf = 0; nf < 16; ++nf) {
        int col = nf * 16 + (lane & 15);
        float badd = HEADS ? bias[col] : 0.f;
#pragma unroll
        for (int r = 0; r < 4; ++r) {
            int row = row0 + kg * 4 + r;
            if (row < M) C[(size_t)row * HD + col] = acc[nf][r] + badd;
        }
    }
}

// ---------------- launch ----------------

static inline size_t align_up(size_t x, size_t a) { return (x + a - 1) & ~(a - 1); }

extern "C" void kernel_launch(void* const* d_in, const int* in_sizes, int n_in,
                              void* d_out, int out_size, void* d_ws, size_t ws_size,
                              hipStream_t stream) {
    const int N = in_sizes[0] / HD;
    const int E = in_sizes[1] / 2;

    const float* x   = (const float*)d_in[0];
    const int*   ei  = (const int*)d_in[1];
    const float* W1  = (const float*)d_in[2];
    const float* W11 = (const float*)d_in[3];
    const float* W2  = (const float*)d_in[4];
    const float* W3  = (const float*)d_in[5];
    const float* b1  = (const float*)d_in[6];
    const float* b11 = (const float*)d_in[7];
    const float* b2  = (const float*)d_in[8];
    const float* b3  = (const float*)d_in[9];

    float* out2 = (float*)d_out;
    float* out3 = out2 + (size_t)N * HD;

    // workspace carve (~44 MB)
    char* p = (char*)d_ws;
    int*   deg    = (int*)p;   p += align_up((size_t)N * 4, 256);
    int*   offs   = (int*)p;   p += align_up((size_t)(N + 1) * 4, 256);
    int*   cursor = (int*)p;   p += align_up((size_t)N * 4, 256);
    float* dinv   = (float*)p; p += align_up((size_t)N * 4, 256);
    int*   csr    = (int*)p;   p += align_up((size_t)(E + N) * 4, 256);
    unsigned short* pkhi = (unsigned short*)p; p += align_up((size_t)4 * 65536 * 2, 256);
    unsigned short* pklo = (unsigned short*)p; p += align_up((size_t)4 * 65536 * 2, 256);
    float* bufZ = (float*)p;   p += align_up((size_t)N * HD * 4, 256);
    unsigned short* bufThi = (unsigned short*)p; p += align_up((size_t)N * HD * 2, 256);
    unsigned short* bufTlo = (unsigned short*)p; p += align_up((size_t)N * HD * 2, 256);
    // g reuses bufZ (z2 dead by then): 2 x 10.24MB fits in 20.48MB
    unsigned short* bufGhi = (unsigned short*)bufZ;
    unsigned short* bufGlo = bufGhi + (size_t)N * HD;
    (void)ws_size; (void)n_in; (void)out_size;

    // --- CSR of incoming edges (with self loops); dinv from scan ---
    init_deg_kernel<<<(N + 255) / 256, 256, 0, stream>>>(deg, cursor, N);
    count_deg_kernel<<<(E + 255) / 256, 256, 0, stream>>>(ei + E, E, deg);
    scan_kernel<<<1, 1024, 0, stream>>>(deg, offs, dinv, N);
    fill_csr_kernel<<<(E + N + 255) / 256, 256, 0, stream>>>(ei, E, N, offs, cursor, csr);

    // --- pre-pack weights, convert x ---
    packW_kernel<<<128, 256, 0, stream>>>(W1, W11, W2, W3, pkhi, pklo);
    convx_kernel<<<(N * 32 + 255) / 256, 256, 0, stream>>>(x, dinv, bufThi, bufTlo, N);

    const int gx = (N + 63) / 64;
    const int agg_blocks = (N + 3) / 4;

    // layer 1: z1 = Xs @ W1 ; t1 = split(dinv*relu(dinv*sum + b1))
    gemm_mfma_kernel<false><<<dim3(gx, 1), 256, 0, stream>>>(
        bufThi, bufTlo, pkhi + 0 * 65536, pklo + 0 * 65536, nullptr, nullptr, bufZ, nullptr, N);
    agg_relu_split_kernel<<<agg_blocks, 256, 0, stream>>>(bufZ, csr, offs, dinv, b1, bufThi, bufTlo, N);

    // layer 2: z2 = t1 @ W1_1 ; t2 = split(dinv*relu(dinv*sum + b1_1))
    gemm_mfma_kernel<false><<<dim3(gx, 1), 256, 0, stream>>>(
        bufThi, bufTlo, pkhi + 1 * 65536, pklo + 1 * 65536, nullptr, nullptr, bufZ, nullptr, N);
    agg_relu_split_kernel<<<agg_blocks, 256, 0, stream>>>(bufZ, csr, offs, dinv, b11, bufThi, bufTlo, N);

    // shared agg: g = split(dinv * sum(t2))
    agg_pair_kernel<<<agg_blocks, 256, 0, stream>>>(bufThi, bufTlo, csr, offs, dinv, bufGhi, bufGlo, N);

    // fused heads: out2 = g@W2+b2 ; out3 = g@W3+b3  (grid.y selects head)
    gemm_mfma_kernel<true><<<dim3(gx, 2), 256, 0, stream>>>(
        bufGhi, bufGlo, pkhi + 2 * 65536, pklo + 2 * 65536, b2, b3, out2, out3, N);
}

// Round 9
// 314.271 us; speedup vs baseline: 1.2926x; 1.2926x over previous
//
#include <hip/hip_runtime.h>
#include <math.h>

#define HD 256   // hidden dim (fixed per problem)

typedef short bf16x8 __attribute__((ext_vector_type(8)));
typedef float f32x4  __attribute__((ext_vector_type(4)));

__device__ __forceinline__ unsigned short f2bf(float f) {   // RNE f32->bf16
    unsigned u = __builtin_bit_cast(unsigned, f);
    unsigned r = (u + 0x7fffu + ((u >> 16) & 1u)) >> 16;
    return (unsigned short)r;
}
__device__ __forceinline__ float bf2f(unsigned b) {
    return __builtin_bit_cast(float, (b & 0xffffu) << 16);
}

// ---------------- CSR build ----------------

__global__ void init_deg_kernel(int* __restrict__ deg, int* __restrict__ cursor, int n) {
    int i = blockIdx.x * blockDim.x + threadIdx.x;
    if (i < n) { deg[i] = 1; cursor[i] = 0; }   // 1 = self loop
}

__global__ void count_deg_kernel(const int* __restrict__ col, int E, int* __restrict__ deg) {
    int e = blockIdx.x * blockDim.x + threadIdx.x;
    if (e < E) atomicAdd(&deg[col[e]], 1);
}

__global__ __launch_bounds__(1024) void scan_kernel(const int* __restrict__ deg,
                                                    int* __restrict__ offs,
                                                    float* __restrict__ dinv, int n) {
    __shared__ int ps[1024];
    int tid = threadIdx.x;
    int chunk = (n + 1023) >> 10;
    int beg = tid * chunk;
    int end = min(beg + chunk, n);
    int s = 0;
    for (int i = beg; i < end; ++i) s += deg[i];
    ps[tid] = s;
    __syncthreads();
    for (int off = 1; off < 1024; off <<= 1) {
        int t = (tid >= off) ? ps[tid - off] : 0;
        __syncthreads();
        ps[tid] += t;
        __syncthreads();
    }
    int run = ps[tid] - s;  // exclusive prefix
    for (int i = beg; i < end; ++i) {
        offs[i] = run;
        run += deg[i];
        dinv[i] = rsqrtf((float)deg[i]);
    }
    if (tid == 1023) offs[n] = ps[1023];
}

__global__ void fill_csr_kernel(const int* __restrict__ ei, int E, int N,
                                const int* __restrict__ offs,
                                int* __restrict__ cursor, int* __restrict__ csr) {
    int idx = blockIdx.x * blockDim.x + threadIdx.x;
    int tot = E + N;
    if (idx >= tot) return;
    int r, c;
    if (idx < E) { r = ei[idx]; c = ei[E + idx]; }
    else         { r = c = idx - E; }                 // self loop
    int slot = atomicAdd(&cursor[c], 1);
    csr[offs[c] + slot] = r;
}

// ---------------- W pre-pack: f32 W[256][256] -> MFMA-fragment-linear bf16 hi/lo ----------------
// Frag (nc,kc): 16x16x32 B-operand tile, cols nc*16..+15, k kc*32..+31.
// Slot rule (same as A side, so any intra-frag k permutation cancels):
//   lane l, elem e  <->  W[kc*32 + 8*(l>>4) + e][nc*16 + (l&15)]
// Layout (nc-major): pk[mat][nc][kc][lane][e], 65536 elems per matrix.

__global__ __launch_bounds__(256) void packW_kernel(const float* __restrict__ W0,
                                                    const float* __restrict__ W1,
                                                    const float* __restrict__ W2,
                                                    const float* __restrict__ W3,
                                                    unsigned short* __restrict__ pkhi,
                                                    unsigned short* __restrict__ pklo) {
    int gid = blockIdx.x * 256 + threadIdx.x;   // 32768 threads total
    int mat  = gid >> 13;
    int rem  = gid & 8191;
    int nc   = rem >> 9;
    int kc   = (rem >> 6) & 7;
    int lane = rem & 63;
    const float* W = (mat == 0) ? W0 : (mat == 1) ? W1 : (mat == 2) ? W2 : W3;
    int col = nc * 16 + (lane & 15);
    int kb  = kc * 32 + (lane >> 4) * 8;
    alignas(16) unsigned short h[8], l[8];
#pragma unroll
    for (int e = 0; e < 8; ++e) {
        float w = W[(size_t)(kb + e) * HD + col];
        unsigned short hb = f2bf(w);
        h[e] = hb;
        l[e] = f2bf(w - bf2f(hb));
    }
    size_t off = (size_t)mat * 65536 + ((size_t)(nc * 8 + kc) * 64 + lane) * 8;
    *(uint4*)&pkhi[off] = *(const uint4*)h;
    *(uint4*)&pklo[off] = *(const uint4*)l;
}

// ---------------- x conversion: thi/tlo = split(dinv[row] * x[row][:]) ----------------

__global__ __launch_bounds__(256) void convx_kernel(const float* __restrict__ x,
                                                    const float* __restrict__ dinv,
                                                    unsigned short* __restrict__ thi,
                                                    unsigned short* __restrict__ tlo, int N) {
    int gid = blockIdx.x * 256 + threadIdx.x;   // N*32, 8 elems each
    if (gid >= N * 32) return;
    int row = gid >> 5;
    int c8  = (gid & 31) * 8;
    float s = dinv[row];
    const float4* xp = (const float4*)(x + (size_t)row * HD + c8);
    float4 v0 = xp[0], v1 = xp[1];
    float vals[8] = {v0.x, v0.y, v0.z, v0.w, v1.x, v1.y, v1.z, v1.w};
    alignas(16) unsigned short h[8], l[8];
#pragma unroll
    for (int e = 0; e < 8; ++e) {
        float t = vals[e] * s;
        unsigned short hb = f2bf(t);
        h[e] = hb;
        l[e] = f2bf(t - bf2f(hb));
    }
    size_t off = (size_t)row * HD + c8;
    *(uint4*)&thi[off] = *(const uint4*)h;
    *(uint4*)&tlo[off] = *(const uint4*)l;
}

// ---------------- aggregation (hidden layers) ----------------
// read f32 z, gather row-sum, t = dinv*relu(dinv*S + b), write split bf16 hi/lo.

__global__ __launch_bounds__(256) void agg_relu_split_kernel(const float* __restrict__ z,
                                                             const int* __restrict__ csr,
                                                             const int* __restrict__ offs,
                                                             const float* __restrict__ dinv,
                                                             const float* __restrict__ bias,
                                                             unsigned short* __restrict__ thi,
                                                             unsigned short* __restrict__ tlo, int N) {
    int gid  = blockIdx.x * blockDim.x + threadIdx.x;
    int v    = gid >> 6;
    int lane = gid & 63;
    if (v >= N) return;

    int beg = offs[v];
    int end = offs[v + 1];
    const float4* hp = (const float4*)z;

    float4 acc = make_float4(0.f, 0.f, 0.f, 0.f);
    int i = beg;
    for (; i + 4 <= end; i += 4) {
        int u0 = csr[i], u1 = csr[i + 1], u2 = csr[i + 2], u3 = csr[i + 3];
        float4 r0 = hp[(size_t)u0 * 64 + lane];
        float4 r1 = hp[(size_t)u1 * 64 + lane];
        float4 r2 = hp[(size_t)u2 * 64 + lane];
        float4 r3 = hp[(size_t)u3 * 64 + lane];
        acc.x += (r0.x + r1.x) + (r2.x + r3.x);
        acc.y += (r0.y + r1.y) + (r2.y + r3.y);
        acc.z += (r0.z + r1.z) + (r2.z + r3.z);
        acc.w += (r0.w + r1.w) + (r2.w + r3.w);
    }
    for (; i < end; ++i) {
        int u = csr[i];
        float4 r = hp[(size_t)u * 64 + lane];
        acc.x += r.x; acc.y += r.y; acc.z += r.z; acc.w += r.w;
    }

    float dv = dinv[v];
    float4 bv = ((const float4*)bias)[lane];
    float t[4];
    t[0] = dv * fmaxf(fmaf(dv, acc.x, bv.x), 0.f);
    t[1] = dv * fmaxf(fmaf(dv, acc.y, bv.y), 0.f);
    t[2] = dv * fmaxf(fmaf(dv, acc.z, bv.z), 0.f);
    t[3] = dv * fmaxf(fmaf(dv, acc.w, bv.w), 0.f);
    alignas(8) unsigned short h[4], l[4];
#pragma unroll
    for (int e = 0; e < 4; ++e) {
        unsigned short hb = f2bf(t[e]);
        h[e] = hb;
        l[e] = f2bf(t[e] - bf2f(hb));
    }
    size_t off = (size_t)v * HD + lane * 4;
    *(uint2*)&thi[off] = *(const uint2*)h;
    *(uint2*)&tlo[off] = *(const uint2*)l;
}

// ---------------- shared aggregation: g = dinv * sum(t2) ----------------

__global__ __launch_bounds__(256) void agg_pair_kernel(const unsigned short* __restrict__ thi,
                                                       const unsigned short* __restrict__ tlo,
                                                       const int* __restrict__ csr,
                                                       const int* __restrict__ offs,
                                                       const float* __restrict__ dinv,
                                                       unsigned short* __restrict__ ghi,
                                                       unsigned short* __restrict__ glo, int N) {
    int gid  = blockIdx.x * blockDim.x + threadIdx.x;
    int v    = gid >> 6;
    int lane = gid & 63;
    if (v >= N) return;

    int beg = offs[v];
    int end = offs[v + 1];
    const uint2* hp = (const uint2*)thi;   // row = 64 uint2 (4 bf16 each)
    const uint2* lp = (const uint2*)tlo;

    float a0 = 0.f, a1 = 0.f, a2 = 0.f, a3 = 0.f;
    int i = beg;
    for (; i + 2 <= end; i += 2) {
        int u0 = csr[i], u1 = csr[i + 1];
        uint2 h0 = hp[(size_t)u0 * 64 + lane];
        uint2 l0 = lp[(size_t)u0 * 64 + lane];
        uint2 h1 = hp[(size_t)u1 * 64 + lane];
        uint2 l1 = lp[(size_t)u1 * 64 + lane];
        a0 += (bf2f(h0.x) + bf2f(l0.x)) + (bf2f(h1.x) + bf2f(l1.x));
        a1 += (bf2f(h0.x >> 16) + bf2f(l0.x >> 16)) + (bf2f(h1.x >> 16) + bf2f(l1.x >> 16));
        a2 += (bf2f(h0.y) + bf2f(l0.y)) + (bf2f(h1.y) + bf2f(l1.y));
        a3 += (bf2f(h0.y >> 16) + bf2f(l0.y >> 16)) + (bf2f(h1.y >> 16) + bf2f(l1.y >> 16));
    }
    for (; i < end; ++i) {
        int u = csr[i];
        uint2 h0 = hp[(size_t)u * 64 + lane];
        uint2 l0 = lp[(size_t)u * 64 + lane];
        a0 += bf2f(h0.x) + bf2f(l0.x);
        a1 += bf2f(h0.x >> 16) + bf2f(l0.x >> 16);
        a2 += bf2f(h0.y) + bf2f(l0.y);
        a3 += bf2f(h0.y >> 16) + bf2f(l0.y >> 16);
    }

    float dv = dinv[v];
    float t[4] = {dv * a0, dv * a1, dv * a2, dv * a3};
    alignas(8) unsigned short h[4], l[4];
#pragma unroll
    for (int e = 0; e < 4; ++e) {
        unsigned short hb = f2bf(t[e]);
        h[e] = hb;
        l[e] = f2bf(t[e] - bf2f(hb));
    }
    size_t off = (size_t)v * HD + lane * 4;
    *(uint2*)&ghi[off] = *(const uint2*)h;
    *(uint2*)&glo[off] = *(const uint2*)l;
}

// ---------------- MFMA GEMM: C[M,256] = (Ahi+Alo) @ (Whi+Wlo), 3-term split ----------------
// R6 structure (16 rows x 64 cols per wave, acc=16 VGPR, no LDS, W streamed from
// L2) + XCD-AWARE SWIZZLE: 1D grid, id = xcd + 8*(by + NBY*g), bx = xcd + 8*g.
// All NBY col/head-blocks of one row-group run BACK-TO-BACK on the SAME XCD ->
// A hi/lo is HBM-fetched once and L2-hit for the rest (reuse distance ~1 block).
// NBY=4: hidden (by = col-group). NBY=8: heads (sel=by>>2 picks W2/W3, nc0=by&3).
// mfma_f32_16x16x32_bf16: D col=lane&15, row=(lane>>4)*4+reg  [m89-verified].

template<int NBY>
__global__ __launch_bounds__(256)
void gemm_mfma_kernel(const unsigned short* __restrict__ Ahi,
                      const unsigned short* __restrict__ Alo,
                      const unsigned short* __restrict__ pkhi,
                      const unsigned short* __restrict__ pklo,
                      const float* __restrict__ ba,
                      const float* __restrict__ bb,
                      float* __restrict__ Ca,
                      float* __restrict__ Cb, int M, int gx) {
    // swizzle decode
    const int id  = blockIdx.x;
    const int xcd = id & 7;
    const int t   = id >> 3;
    const int by  = t & (NBY - 1);
    const int g   = t / NBY;
    const int bx  = xcd + (g << 3);
    if (bx >= gx) return;

    const int tid  = threadIdx.x;
    const int lane = tid & 63;
    const int wave = tid >> 6;

    const int sel = (NBY == 8) ? (by >> 2) : 0;        // heads: 0->W2/out2, 1->W3/out3
    const int nc0 = ((NBY == 8) ? (by & 3) : by) * 4;
    const unsigned short* ph = pkhi + (size_t)sel * 65536;
    const unsigned short* pl = pklo + (size_t)sel * 65536;
    float*       C    = sel ? Cb : Ca;
    const float* bias = sel ? bb : ba;

    const int row0 = bx * 64 + wave * 16;
    const int rowA = min(row0 + (lane & 15), M - 1);   // clamp: garbage only feeds unstored rows
    const int kg   = lane >> 4;

    const unsigned short* aH = Ahi + (size_t)rowA * HD + kg * 8;
    const unsigned short* aL = Alo + (size_t)rowA * HD + kg * 8;
    const size_t wbase = ((size_t)(nc0 * 8) * 64 + (size_t)lane) * 8;

    f32x4 acc[4];
#pragma unroll
    for (int nf = 0; nf < 4; ++nf) acc[nf] = (f32x4)0.f;

#pragma unroll 2
    for (int kc = 0; kc < 8; ++kc) {
        bf16x8 ah = *(const bf16x8*)(aH + kc * 32);
        bf16x8 al = *(const bf16x8*)(aL + kc * 32);
        size_t wb = wbase + (size_t)kc * 512;          // kc stride = 64*8
        bf16x8 wh[4], wl[4];
#pragma unroll
        for (int nf = 0; nf < 4; ++nf) {
            wh[nf] = *(const bf16x8*)(ph + wb + (size_t)nf * 4096);  // nf stride = 8*64*8
            wl[nf] = *(const bf16x8*)(pl + wb + (size_t)nf * 4096);
        }
#pragma unroll
        for (int nf = 0; nf < 4; ++nf) {
            acc[nf] = __builtin_amdgcn_mfma_f32_16x16x32_bf16(ah, wh[nf], acc[nf], 0, 0, 0);
            acc[nf] = __builtin_amdgcn_mfma_f32_16x16x32_bf16(ah, wl[nf], acc[nf], 0, 0, 0);
            acc[nf] = __builtin_amdgcn_mfma_f32_16x16x32_bf16(al, wh[nf], acc[nf], 0, 0, 0);
        }
    }

#pragma unroll
    for (int nf = 0; nf < 4; ++nf) {
        int col = (nc0 + nf) * 16 + (lane & 15);
        float badd = (NBY == 8) ? bias[col] : 0.f;
#pragma unroll
        for (int r = 0; r < 4; ++r) {
            int row = row0 + kg * 4 + r;
            if (row < M) C[(size_t)row * HD + col] = acc[nf][r] + badd;
        }
    }
}

// ---------------- launch ----------------

static inline size_t align_up(size_t x, size_t a) { return (x + a - 1) & ~(a - 1); }

extern "C" void kernel_launch(void* const* d_in, const int* in_sizes, int n_in,
                              void* d_out, int out_size, void* d_ws, size_t ws_size,
                              hipStream_t stream) {
    const int N = in_sizes[0] / HD;
    const int E = in_sizes[1] / 2;

    const float* x   = (const float*)d_in[0];
    const int*   ei  = (const int*)d_in[1];
    const float* W1  = (const float*)d_in[2];
    const float* W11 = (const float*)d_in[3];
    const float* W2  = (const float*)d_in[4];
    const float* W3  = (const float*)d_in[5];
    const float* b1  = (const float*)d_in[6];
    const float* b11 = (const float*)d_in[7];
    const float* b2  = (const float*)d_in[8];
    const float* b3  = (const float*)d_in[9];

    float* out2 = (float*)d_out;
    float* out3 = out2 + (size_t)N * HD;

    // workspace carve (~44 MB)
    char* p = (char*)d_ws;
    int*   deg    = (int*)p;   p += align_up((size_t)N * 4, 256);
    int*   offs   = (int*)p;   p += align_up((size_t)(N + 1) * 4, 256);
    int*   cursor = (int*)p;   p += align_up((size_t)N * 4, 256);
    float* dinv   = (float*)p; p += align_up((size_t)N * 4, 256);
    int*   csr    = (int*)p;   p += align_up((size_t)(E + N) * 4, 256);
    unsigned short* pkhi = (unsigned short*)p; p += align_up((size_t)4 * 65536 * 2, 256);
    unsigned short* pklo = (unsigned short*)p; p += align_up((size_t)4 * 65536 * 2, 256);
    float* bufZ = (float*)p;   p += align_up((size_t)N * HD * 4, 256);
    unsigned short* bufThi = (unsigned short*)p; p += align_up((size_t)N * HD * 2, 256);
    unsigned short* bufTlo = (unsigned short*)p; p += align_up((size_t)N * HD * 2, 256);
    // g reuses bufZ (z2 dead by then): 2 x 10.24MB fits in 20.48MB
    unsigned short* bufGhi = (unsigned short*)bufZ;
    unsigned short* bufGlo = bufGhi + (size_t)N * HD;
    (void)ws_size; (void)n_in; (void)out_size;

    // --- CSR of incoming edges (with self loops); dinv from scan ---
    init_deg_kernel<<<(N + 255) / 256, 256, 0, stream>>>(deg, cursor, N);
    count_deg_kernel<<<(E + 255) / 256, 256, 0, stream>>>(ei + E, E, deg);
    scan_kernel<<<1, 1024, 0, stream>>>(deg, offs, dinv, N);
    fill_csr_kernel<<<(E + N + 255) / 256, 256, 0, stream>>>(ei, E, N, offs, cursor, csr);

    // --- pre-pack weights, convert x ---
    packW_kernel<<<128, 256, 0, stream>>>(W1, W11, W2, W3, pkhi, pklo);
    convx_kernel<<<(N * 32 + 255) / 256, 256, 0, stream>>>(x, dinv, bufThi, bufTlo, N);

    const int gx  = (N + 63) / 64;            // 313 real row-groups
    const int gxp = ((gx + 7) / 8) * 8;       // padded to 320 for bijective swizzle
    const int agg_blocks = (N + 3) / 4;

    // layer 1: z1 = Xs @ W1 ; t1 = split(dinv*relu(dinv*sum + b1))
    gemm_mfma_kernel<4><<<gxp * 4, 256, 0, stream>>>(
        bufThi, bufTlo, pkhi + 0 * 65536, pklo + 0 * 65536, nullptr, nullptr, bufZ, nullptr, N, gx);
    agg_relu_split_kernel<<<agg_blocks, 256, 0, stream>>>(bufZ, csr, offs, dinv, b1, bufThi, bufTlo, N);

    // layer 2: z2 = t1 @ W1_1 ; t2 = split(dinv*relu(dinv*sum + b1_1))
    gemm_mfma_kernel<4><<<gxp * 4, 256, 0, stream>>>(
        bufThi, bufTlo, pkhi + 1 * 65536, pklo + 1 * 65536, nullptr, nullptr, bufZ, nullptr, N, gx);
    agg_relu_split_kernel<<<agg_blocks, 256, 0, stream>>>(bufZ, csr, offs, dinv, b11, bufThi, bufTlo, N);

    // shared agg: g = split(dinv * sum(t2))
    agg_pair_kernel<<<agg_blocks, 256, 0, stream>>>(bufThi, bufTlo, csr, offs, dinv, bufGhi, bufGlo, N);

    // fused heads: out2 = g@W2+b2 ; out3 = g@W3+b3  (by 0-3 -> W2, 4-7 -> W3)
    gemm_mfma_kernel<8><<<gxp * 8, 256, 0, stream>>>(
        bufGhi, bufGlo, pkhi + 2 * 65536, pklo + 2 * 65536, b2, b3, out2, out3, N, gx);
}

// Round 10
// 286.841 us; speedup vs baseline: 1.4162x; 1.0956x over previous
//
#include <hip/hip_runtime.h>
#include <math.h>

#define HD 256   // hidden dim (fixed per problem)

typedef short bf16x8 __attribute__((ext_vector_type(8)));
typedef float f32x4  __attribute__((ext_vector_type(4)));

__device__ __forceinline__ unsigned short f2bf(float f) {   // RNE f32->bf16
    unsigned u = __builtin_bit_cast(unsigned, f);
    unsigned r = (u + 0x7fffu + ((u >> 16) & 1u)) >> 16;
    return (unsigned short)r;
}
__device__ __forceinline__ float bf2f(unsigned b) {
    return __builtin_bit_cast(float, (b & 0xffffu) << 16);
}

// ---------------- CSR build ----------------

__global__ void init_deg_kernel(int* __restrict__ deg, int* __restrict__ cursor, int n) {
    int i = blockIdx.x * blockDim.x + threadIdx.x;
    if (i < n) { deg[i] = 1; cursor[i] = 0; }   // 1 = self loop
}

__global__ void count_deg_kernel(const int* __restrict__ col, int E, int* __restrict__ deg) {
    int e = blockIdx.x * blockDim.x + threadIdx.x;
    if (e < E) atomicAdd(&deg[col[e]], 1);
}

__global__ __launch_bounds__(1024) void scan_kernel(const int* __restrict__ deg,
                                                    int* __restrict__ offs,
                                                    float* __restrict__ dinv, int n) {
    __shared__ int ps[1024];
    int tid = threadIdx.x;
    int chunk = (n + 1023) >> 10;
    int beg = tid * chunk;
    int end = min(beg + chunk, n);
    int s = 0;
    for (int i = beg; i < end; ++i) s += deg[i];
    ps[tid] = s;
    __syncthreads();
    for (int off = 1; off < 1024; off <<= 1) {
        int t = (tid >= off) ? ps[tid - off] : 0;
        __syncthreads();
        ps[tid] += t;
        __syncthreads();
    }
    int run = ps[tid] - s;  // exclusive prefix
    for (int i = beg; i < end; ++i) {
        offs[i] = run;
        run += deg[i];
        dinv[i] = rsqrtf((float)deg[i]);
    }
    if (tid == 1023) offs[n] = ps[1023];
}

__global__ void fill_csr_kernel(const int* __restrict__ ei, int E, int N,
                                const int* __restrict__ offs,
                                int* __restrict__ cursor, int* __restrict__ csr) {
    int idx = blockIdx.x * blockDim.x + threadIdx.x;
    int tot = E + N;
    if (idx >= tot) return;
    int r, c;
    if (idx < E) { r = ei[idx]; c = ei[E + idx]; }
    else         { r = c = idx - E; }                 // self loop
    int slot = atomicAdd(&cursor[c], 1);
    csr[offs[c] + slot] = r;
}

// ---------------- W pre-pack: f32 W[256][256] -> MFMA-fragment-linear bf16 hi/lo ----------------
// Frag (nc,kc): 16x16x32 B-operand tile, cols nc*16..+15, k kc*32..+31.
// Slot rule (same as A side, so any intra-frag k permutation cancels):
//   lane l, elem e  <->  W[kc*32 + 8*(l>>4) + e][nc*16 + (l&15)]
// Layout (nc-major): pk[mat][nc][kc][lane][e], 65536 elems per matrix.

__global__ __launch_bounds__(256) void packW_kernel(const float* __restrict__ W0,
                                                    const float* __restrict__ W1,
                                                    const float* __restrict__ W2,
                                                    const float* __restrict__ W3,
                                                    unsigned short* __restrict__ pkhi,
                                                    unsigned short* __restrict__ pklo) {
    int gid = blockIdx.x * 256 + threadIdx.x;   // 32768 threads total
    int mat  = gid >> 13;
    int rem  = gid & 8191;
    int nc   = rem >> 9;
    int kc   = (rem >> 6) & 7;
    int lane = rem & 63;
    const float* W = (mat == 0) ? W0 : (mat == 1) ? W1 : (mat == 2) ? W2 : W3;
    int col = nc * 16 + (lane & 15);
    int kb  = kc * 32 + (lane >> 4) * 8;
    alignas(16) unsigned short h[8], l[8];
#pragma unroll
    for (int e = 0; e < 8; ++e) {
        float w = W[(size_t)(kb + e) * HD + col];
        unsigned short hb = f2bf(w);
        h[e] = hb;
        l[e] = f2bf(w - bf2f(hb));
    }
    size_t off = (size_t)mat * 65536 + ((size_t)(nc * 8 + kc) * 64 + lane) * 8;
    *(uint4*)&pkhi[off] = *(const uint4*)h;
    *(uint4*)&pklo[off] = *(const uint4*)l;
}

// ---------------- x conversion: thi/tlo = split(dinv[row] * x[row][:]) ----------------

__global__ __launch_bounds__(256) void convx_kernel(const float* __restrict__ x,
                                                    const float* __restrict__ dinv,
                                                    unsigned short* __restrict__ thi,
                                                    unsigned short* __restrict__ tlo, int N) {
    int gid = blockIdx.x * 256 + threadIdx.x;   // N*32, 8 elems each
    if (gid >= N * 32) return;
    int row = gid >> 5;
    int c8  = (gid & 31) * 8;
    float s = dinv[row];
    const float4* xp = (const float4*)(x + (size_t)row * HD + c8);
    float4 v0 = xp[0], v1 = xp[1];
    float vals[8] = {v0.x, v0.y, v0.z, v0.w, v1.x, v1.y, v1.z, v1.w};
    alignas(16) unsigned short h[8], l[8];
#pragma unroll
    for (int e = 0; e < 8; ++e) {
        float t = vals[e] * s;
        unsigned short hb = f2bf(t);
        h[e] = hb;
        l[e] = f2bf(t - bf2f(hb));
    }
    size_t off = (size_t)row * HD + c8;
    *(uint4*)&thi[off] = *(const uint4*)h;
    *(uint4*)&tlo[off] = *(const uint4*)l;
}

// ---------------- aggregation (hidden layers) ----------------
// read f32 z, gather row-sum, t = dinv*relu(dinv*S + b), write split bf16 hi/lo.

__global__ __launch_bounds__(256) void agg_relu_split_kernel(const float* __restrict__ z,
                                                             const int* __restrict__ csr,
                                                             const int* __restrict__ offs,
                                                             const float* __restrict__ dinv,
                                                             const float* __restrict__ bias,
                                                             unsigned short* __restrict__ thi,
                                                             unsigned short* __restrict__ tlo, int N) {
    int gid  = blockIdx.x * blockDim.x + threadIdx.x;
    int v    = gid >> 6;
    int lane = gid & 63;
    if (v >= N) return;

    int beg = offs[v];
    int end = offs[v + 1];
    const float4* hp = (const float4*)z;

    float4 acc = make_float4(0.f, 0.f, 0.f, 0.f);
    int i = beg;
    for (; i + 4 <= end; i += 4) {
        int u0 = csr[i], u1 = csr[i + 1], u2 = csr[i + 2], u3 = csr[i + 3];
        float4 r0 = hp[(size_t)u0 * 64 + lane];
        float4 r1 = hp[(size_t)u1 * 64 + lane];
        float4 r2 = hp[(size_t)u2 * 64 + lane];
        float4 r3 = hp[(size_t)u3 * 64 + lane];
        acc.x += (r0.x + r1.x) + (r2.x + r3.x);
        acc.y += (r0.y + r1.y) + (r2.y + r3.y);
        acc.z += (r0.z + r1.z) + (r2.z + r3.z);
        acc.w += (r0.w + r1.w) + (r2.w + r3.w);
    }
    for (; i < end; ++i) {
        int u = csr[i];
        float4 r = hp[(size_t)u * 64 + lane];
        acc.x += r.x; acc.y += r.y; acc.z += r.z; acc.w += r.w;
    }

    float dv = dinv[v];
    float4 bv = ((const float4*)bias)[lane];
    float t[4];
    t[0] = dv * fmaxf(fmaf(dv, acc.x, bv.x), 0.f);
    t[1] = dv * fmaxf(fmaf(dv, acc.y, bv.y), 0.f);
    t[2] = dv * fmaxf(fmaf(dv, acc.z, bv.z), 0.f);
    t[3] = dv * fmaxf(fmaf(dv, acc.w, bv.w), 0.f);
    alignas(8) unsigned short h[4], l[4];
#pragma unroll
    for (int e = 0; e < 4; ++e) {
        unsigned short hb = f2bf(t[e]);
        h[e] = hb;
        l[e] = f2bf(t[e] - bf2f(hb));
    }
    size_t off = (size_t)v * HD + lane * 4;
    *(uint2*)&thi[off] = *(const uint2*)h;
    *(uint2*)&tlo[off] = *(const uint2*)l;
}

// ---------------- shared aggregation: g = dinv * sum(t2) ----------------

__global__ __launch_bounds__(256) void agg_pair_kernel(const unsigned short* __restrict__ thi,
                                                       const unsigned short* __restrict__ tlo,
                                                       const int* __restrict__ csr,
                                                       const int* __restrict__ offs,
                                                       const float* __restrict__ dinv,
                                                       unsigned short* __restrict__ ghi,
                                                       unsigned short* __restrict__ glo, int N) {
    int gid  = blockIdx.x * blockDim.x + threadIdx.x;
    int v    = gid >> 6;
    int lane = gid & 63;
    if (v >= N) return;

    int beg = offs[v];
    int end = offs[v + 1];
    const uint2* hp = (const uint2*)thi;   // row = 64 uint2 (4 bf16 each)
    const uint2* lp = (const uint2*)tlo;

    float a0 = 0.f, a1 = 0.f, a2 = 0.f, a3 = 0.f;
    int i = beg;
    for (; i + 2 <= end; i += 2) {
        int u0 = csr[i], u1 = csr[i + 1];
        uint2 h0 = hp[(size_t)u0 * 64 + lane];
        uint2 l0 = lp[(size_t)u0 * 64 + lane];
        uint2 h1 = hp[(size_t)u1 * 64 + lane];
        uint2 l1 = lp[(size_t)u1 * 64 + lane];
        a0 += (bf2f(h0.x) + bf2f(l0.x)) + (bf2f(h1.x) + bf2f(l1.x));
        a1 += (bf2f(h0.x >> 16) + bf2f(l0.x >> 16)) + (bf2f(h1.x >> 16) + bf2f(l1.x >> 16));
        a2 += (bf2f(h0.y) + bf2f(l0.y)) + (bf2f(h1.y) + bf2f(l1.y));
        a3 += (bf2f(h0.y >> 16) + bf2f(l0.y >> 16)) + (bf2f(h1.y >> 16) + bf2f(l1.y >> 16));
    }
    for (; i < end; ++i) {
        int u = csr[i];
        uint2 h0 = hp[(size_t)u * 64 + lane];
        uint2 l0 = lp[(size_t)u * 64 + lane];
        a0 += bf2f(h0.x) + bf2f(l0.x);
        a1 += bf2f(h0.x >> 16) + bf2f(l0.x >> 16);
        a2 += bf2f(h0.y) + bf2f(l0.y);
        a3 += bf2f(h0.y >> 16) + bf2f(l0.y >> 16);
    }

    float dv = dinv[v];
    float t[4] = {dv * a0, dv * a1, dv * a2, dv * a3};
    alignas(8) unsigned short h[4], l[4];
#pragma unroll
    for (int e = 0; e < 4; ++e) {
        unsigned short hb = f2bf(t[e]);
        h[e] = hb;
        l[e] = f2bf(t[e] - bf2f(hb));
    }
    size_t off = (size_t)v * HD + lane * 4;
    *(uint2*)&ghi[off] = *(const uint2*)h;
    *(uint2*)&glo[off] = *(const uint2*)l;
}

// ---------------- MFMA GEMM: C[M,256] = (Ahi+Alo) @ (Whi+Wlo), 3-term split ----------------
// R9 swizzled structure + W SHARED VIA SMALL LDS:
//  - per block (4 waves, same nc0): each kc's W slice (4 nf x hi/lo = 8 KB) is
//    staged global->reg->LDS once, double-buffered (16 KB total).  4x less W
//    traffic through L1/L2, and the per-kc fragment loads become ds_read_b128.
//  - stage loads issued one kc ahead (T14 split: issue early, ds_write late),
//    A fragments prefetched depth-1 in registers, full unroll for static regs.
//  - XCD swizzle: id = xcd + 8*(by + NBY*g) -> all col/head blocks of a row
//    group run back-to-back on one XCD (A is L2-resident after first by).
// mfma_f32_16x16x32_bf16: D col=lane&15, row=(lane>>4)*4+reg  [m89-verified].

template<int NBY>
__global__ __launch_bounds__(256, 4)
void gemm_mfma_kernel(const unsigned short* __restrict__ Ahi,
                      const unsigned short* __restrict__ Alo,
                      const unsigned short* __restrict__ pkhi,
                      const unsigned short* __restrict__ pklo,
                      const float* __restrict__ ba,
                      const float* __restrict__ bb,
                      float* __restrict__ Ca,
                      float* __restrict__ Cb, int M, int gx) {
    __shared__ unsigned short ldsW[2][2][2048];   // [buf][hi/lo][4nf*64lane*8] = 16 KB

    // swizzle decode
    const int id  = blockIdx.x;
    const int xcd = id & 7;
    const int t   = id >> 3;
    const int by  = t & (NBY - 1);
    const int g   = t / NBY;
    const int bx  = xcd + (g << 3);
    if (bx >= gx) return;

    const int tid  = threadIdx.x;
    const int lane = tid & 63;
    const int wave = tid >> 6;

    const int sel = (NBY == 8) ? (by >> 2) : 0;        // heads: 0->W2/out2, 1->W3/out3
    const int nc0 = ((NBY == 8) ? (by & 3) : by) * 4;
    const unsigned short* ph = pkhi + (size_t)sel * 65536;
    const unsigned short* pl = pklo + (size_t)sel * 65536;
    float*       C    = sel ? Cb : Ca;
    const float* bias = sel ? bb : ba;

    const int row0 = bx * 64 + wave * 16;
    const int rowA = min(row0 + (lane & 15), M - 1);   // clamp: garbage only feeds unstored rows
    const int kg   = lane >> 4;

    const unsigned short* aH = Ahi + (size_t)rowA * HD + kg * 8;
    const unsigned short* aL = Alo + (size_t)rowA * HD + kg * 8;

    // staging role: thread tid covers frag nf=tid>>6, slot lane=tid&63 (16B hi + 16B lo per kc)
    const int snf = tid >> 6;
    const unsigned short* sph = ph + ((size_t)(nc0 + snf) * 8) * 512 + (size_t)(tid & 63) * 8;
    const unsigned short* spl = pl + ((size_t)(nc0 + snf) * 8) * 512 + (size_t)(tid & 63) * 8;

    f32x4 acc[4];
#pragma unroll
    for (int j = 0; j < 4; ++j) acc[j] = (f32x4)0.f;

    // prologue: stage kc=0 into buf0; issue stage loads for kc=1; prefetch A(0)
    uint4 sh = *(const uint4*)(sph);
    uint4 sl = *(const uint4*)(spl);
    *(uint4*)&ldsW[0][0][tid * 8] = sh;
    *(uint4*)&ldsW[0][1][tid * 8] = sl;
    sh = *(const uint4*)(sph + 512);
    sl = *(const uint4*)(spl + 512);

    bf16x8 a_h[2], a_l[2];
    a_h[0] = *(const bf16x8*)(aH);
    a_l[0] = *(const bf16x8*)(aL);
    __syncthreads();   // buf0 ready

#pragma unroll
    for (int kc = 0; kc < 8; ++kc) {
        const int cur = kc & 1;
        // prefetch A for kc+1 (depth-1)
        if (kc < 7) {
            a_h[cur ^ 1] = *(const bf16x8*)(aH + (kc + 1) * 32);
            a_l[cur ^ 1] = *(const bf16x8*)(aL + (kc + 1) * 32);
        }
        // fragment reads from LDS (contiguous 16B/lane -> conflict-free)
        bf16x8 wh[4], wl[4];
#pragma unroll
        for (int j = 0; j < 4; ++j) {
            wh[j] = *(const bf16x8*)&ldsW[cur][0][((size_t)j * 64 + lane) * 8];
            wl[j] = *(const bf16x8*)&ldsW[cur][1][((size_t)j * 64 + lane) * 8];
        }
#pragma unroll
        for (int j = 0; j < 4; ++j) {
            acc[j] = __builtin_amdgcn_mfma_f32_16x16x32_bf16(a_h[cur], wh[j], acc[j], 0, 0, 0);
            acc[j] = __builtin_amdgcn_mfma_f32_16x16x32_bf16(a_h[cur], wl[j], acc[j], 0, 0, 0);
            acc[j] = __builtin_amdgcn_mfma_f32_16x16x32_bf16(a_l[cur], wh[j], acc[j], 0, 0, 0);
        }
        if (kc < 7) {
            // write staged kc+1 into the other buffer (readers of it finished
            // before the previous barrier), then issue stage loads for kc+2
            *(uint4*)&ldsW[cur ^ 1][0][tid * 8] = sh;
            *(uint4*)&ldsW[cur ^ 1][1][tid * 8] = sl;
            if (kc < 6) {
                sh = *(const uint4*)(sph + (size_t)(kc + 2) * 512);
                sl = *(const uint4*)(spl + (size_t)(kc + 2) * 512);
            }
            __syncthreads();
        }
    }

#pragma unroll
    for (int nf = 0; nf < 4; ++nf) {
        int col = (nc0 + nf) * 16 + (lane & 15);
        float badd = (NBY == 8) ? bias[col] : 0.f;
#pragma unroll
        for (int r = 0; r < 4; ++r) {
            int row = row0 + kg * 4 + r;
            if (row < M) C[(size_t)row * HD + col] = acc[nf][r] + badd;
        }
    }
}

// ---------------- launch ----------------

static inline size_t align_up(size_t x, size_t a) { return (x + a - 1) & ~(a - 1); }

extern "C" void kernel_launch(void* const* d_in, const int* in_sizes, int n_in,
                              void* d_out, int out_size, void* d_ws, size_t ws_size,
                              hipStream_t stream) {
    const int N = in_sizes[0] / HD;
    const int E = in_sizes[1] / 2;

    const float* x   = (const float*)d_in[0];
    const int*   ei  = (const int*)d_in[1];
    const float* W1  = (const float*)d_in[2];
    const float* W11 = (const float*)d_in[3];
    const float* W2  = (const float*)d_in[4];
    const float* W3  = (const float*)d_in[5];
    const float* b1  = (const float*)d_in[6];
    const float* b11 = (const float*)d_in[7];
    const float* b2  = (const float*)d_in[8];
    const float* b3  = (const float*)d_in[9];

    float* out2 = (float*)d_out;
    float* out3 = out2 + (size_t)N * HD;

    // workspace carve (~44 MB)
    char* p = (char*)d_ws;
    int*   deg    = (int*)p;   p += align_up((size_t)N * 4, 256);
    int*   offs   = (int*)p;   p += align_up((size_t)(N + 1) * 4, 256);
    int*   cursor = (int*)p;   p += align_up((size_t)N * 4, 256);
    float* dinv   = (float*)p; p += align_up((size_t)N * 4, 256);
    int*   csr    = (int*)p;   p += align_up((size_t)(E + N) * 4, 256);
    unsigned short* pkhi = (unsigned short*)p; p += align_up((size_t)4 * 65536 * 2, 256);
    unsigned short* pklo = (unsigned short*)p; p += align_up((size_t)4 * 65536 * 2, 256);
    float* bufZ = (float*)p;   p += align_up((size_t)N * HD * 4, 256);
    unsigned short* bufThi = (unsigned short*)p; p += align_up((size_t)N * HD * 2, 256);
    unsigned short* bufTlo = (unsigned short*)p; p += align_up((size_t)N * HD * 2, 256);
    // g reuses bufZ (z2 dead by then): 2 x 10.24MB fits in 20.48MB
    unsigned short* bufGhi = (unsigned short*)bufZ;
    unsigned short* bufGlo = bufGhi + (size_t)N * HD;
    (void)ws_size; (void)n_in; (void)out_size;

    // --- CSR of incoming edges (with self loops); dinv from scan ---
    init_deg_kernel<<<(N + 255) / 256, 256, 0, stream>>>(deg, cursor, N);
    count_deg_kernel<<<(E + 255) / 256, 256, 0, stream>>>(ei + E, E, deg);
    scan_kernel<<<1, 1024, 0, stream>>>(deg, offs, dinv, N);
    fill_csr_kernel<<<(E + N + 255) / 256, 256, 0, stream>>>(ei, E, N, offs, cursor, csr);

    // --- pre-pack weights, convert x ---
    packW_kernel<<<128, 256, 0, stream>>>(W1, W11, W2, W3, pkhi, pklo);
    convx_kernel<<<(N * 32 + 255) / 256, 256, 0, stream>>>(x, dinv, bufThi, bufTlo, N);

    const int gx  = (N + 63) / 64;            // 313 real row-groups
    const int gxp = ((gx + 7) / 8) * 8;       // padded to 320 for bijective swizzle
    const int agg_blocks = (N + 3) / 4;

    // layer 1: z1 = Xs @ W1 ; t1 = split(dinv*relu(dinv*sum + b1))
    gemm_mfma_kernel<4><<<gxp * 4, 256, 0, stream>>>(
        bufThi, bufTlo, pkhi + 0 * 65536, pklo + 0 * 65536, nullptr, nullptr, bufZ, nullptr, N, gx);
    agg_relu_split_kernel<<<agg_blocks, 256, 0, stream>>>(bufZ, csr, offs, dinv, b1, bufThi, bufTlo, N);

    // layer 2: z2 = t1 @ W1_1 ; t2 = split(dinv*relu(dinv*sum + b1_1))
    gemm_mfma_kernel<4><<<gxp * 4, 256, 0, stream>>>(
        bufThi, bufTlo, pkhi + 1 * 65536, pklo + 1 * 65536, nullptr, nullptr, bufZ, nullptr, N, gx);
    agg_relu_split_kernel<<<agg_blocks, 256, 0, stream>>>(bufZ, csr, offs, dinv, b11, bufThi, bufTlo, N);

    // shared agg: g = split(dinv * sum(t2))
    agg_pair_kernel<<<agg_blocks, 256, 0, stream>>>(bufThi, bufTlo, csr, offs, dinv, bufGhi, bufGlo, N);

    // fused heads: out2 = g@W2+b2 ; out3 = g@W3+b3  (by 0-3 -> W2, 4-7 -> W3)
    gemm_mfma_kernel<8><<<gxp * 8, 256, 0, stream>>>(
        bufGhi, bufGlo, pkhi + 2 * 65536, pklo + 2 * 65536, b2, b3, out2, out3, N, gx);
}